// Round 5
// baseline (97.788 us; speedup 1.0000x reference)
//
#include <hip/hip_runtime.h>

#define NPIX (384*384)        // 147456
#define NSAMP 32
#define BINS2 2048            // exponent(8) + 4 mantissa bits; l in [0,1) -> bin < 2032
#define THREADS 256
#define BLKROW 36
#define EPB (NPIX / BLKROW)   // 4096 elements per block
#define NIT (EPB / (THREADS * 4))   // 4 float4-iterations per thread
#define FXSCALE 268435456.0f  // 2^28 fixed-point scale for packed bin sums
#define FXINV   3.7252902984619141e-9
#define MASK46  ((1ULL << 46) - 1)
// packed bin: (count << 46) | fixed_point_sum.  Global totals fit:
//   count <= 147456 < 2^18,  sum <= 147456 * 2^28 < 2^46.

#define HIST_U64  ((size_t)NSAMP * 2 * BINS2)   // [samp][type][bin], 1 MB
#define STATS_OFF (HIST_U64 * 8)                // bytes; stats after hist
// stats per samp (stride 4 x 4B): 0=n_pos_r(u32) 1=pos_sum_r(f32) 2=n_pos_a 3=pos_sum_a
#define ZERO_BYTES (STATS_OFF + 1024)

__global__ __launch_bounds__(THREADS) void k_zero(uint4* __restrict__ ws4,
                                                  float* __restrict__ out)
{
    size_t i = (size_t)blockIdx.x * THREADS + threadIdx.x;
    if (i < ZERO_BYTES / 16) ws4[i] = make_uint4(0u, 0u, 0u, 0u);
    if (i == 0) out[0] = 0.f;
}

// One fused pass: reads each of the 5 input arrays exactly once, computes both
// losses per pixel, builds region+affinity 2048-bin packed histograms in LDS,
// flushes via one u64 global atomic per nonzero bin.
__global__ __launch_bounds__(THREADS) void k_hist(
    const float* __restrict__ gt_r, const float* __restrict__ gt_a,
    const float* __restrict__ pr_r, const float* __restrict__ pr_a,
    const float* __restrict__ conf,
    unsigned long long* __restrict__ hist,
    unsigned int* __restrict__ stats_u, float* __restrict__ stats_f)
{
    __shared__ unsigned long long s_hist[2 * BINS2];   // 32 KB
    const int tid = threadIdx.x;
    const int samp = blockIdx.y;

    for (int i = tid; i < 2 * BINS2; i += THREADS) s_hist[i] = 0ULL;
    __syncthreads();

    size_t idx = (size_t)samp * NPIX + (size_t)blockIdx.x * EPB + (size_t)tid * 4;
    unsigned pc_r = 0, pc_a = 0; float ps_r = 0.f, ps_a = 0.f;

    // software-pipelined: current regs loaded, next iteration prefetched
    float4 gr = *(const float4*)(gt_r + idx);
    float4 pr = *(const float4*)(pr_r + idx);
    float4 ga = *(const float4*)(gt_a + idx);
    float4 pa = *(const float4*)(pr_a + idx);
    float4 cf = *(const float4*)(conf + idx);
    #pragma unroll
    for (int it = 0; it < NIT; ++it) {
        float4 gr1, pr1, ga1, pa1, cf1;
        if (it + 1 < NIT) {
            size_t nx = idx + (size_t)THREADS * 4;
            gr1 = *(const float4*)(gt_r + nx);
            pr1 = *(const float4*)(pr_r + nx);
            ga1 = *(const float4*)(gt_a + nx);
            pa1 = *(const float4*)(pr_a + nx);
            cf1 = *(const float4*)(conf + nx);
        }
        float grv[4] = {gr.x, gr.y, gr.z, gr.w};
        float prv[4] = {pr.x, pr.y, pr.z, pr.w};
        float gav[4] = {ga.x, ga.y, ga.z, ga.w};
        float pav[4] = {pa.x, pa.y, pa.z, pa.w};
        float cfv[4] = {cf.x, cf.y, cf.z, cf.w};
        #pragma unroll
        for (int j = 0; j < 4; ++j) {
            float c = cfv[j];
            float dr = prv[j] - grv[j];
            float lr = dr * dr * c;
            if (grv[j] >= 0.1f) { pc_r++; ps_r += lr; }
            else {
                unsigned bin = __float_as_uint(lr) >> 19;
                atomicAdd(&s_hist[bin],
                    (1ULL << 46) | (unsigned long long)(unsigned)(lr * FXSCALE));
            }
            float da = pav[j] - gav[j];
            float la = da * da * c;
            if (gav[j] >= 0.1f) { pc_a++; ps_a += la; }
            else {
                unsigned bin = __float_as_uint(la) >> 19;
                atomicAdd(&s_hist[BINS2 + bin],
                    (1ULL << 46) | (unsigned long long)(unsigned)(la * FXSCALE));
            }
        }
        if (it + 1 < NIT) { gr = gr1; pr = pr1; ga = ga1; pa = pa1; cf = cf1; }
        idx += (size_t)THREADS * 4;
    }

    // wave-reduce positive stats, one global atomic per wave
    for (int off = 32; off; off >>= 1) {
        pc_r += __shfl_down(pc_r, off); ps_r += __shfl_down(ps_r, off);
        pc_a += __shfl_down(pc_a, off); ps_a += __shfl_down(ps_a, off);
    }
    if ((tid & 63) == 0) {
        if (pc_r) { atomicAdd(&stats_u[samp * 4 + 0], pc_r);
                    atomicAdd(&stats_f[samp * 4 + 1], ps_r); }
        if (pc_a) { atomicAdd(&stats_u[samp * 4 + 2], pc_a);
                    atomicAdd(&stats_f[samp * 4 + 3], ps_a); }
    }
    __syncthreads();

    unsigned long long* hrow = hist + (size_t)samp * 2 * BINS2;
    for (int i = tid; i < 2 * BINS2; i += THREADS) {
        unsigned long long v = s_hist[i];
        if (v) atomicAdd(&hrow[i], v);
    }
}

// Per row (samp,type): parallel descending suffix-scan over 2048 bins, find
// boundary bin where cum < k <= cum+cnt, approximate the partial bin by its
// true mean, accumulate the row result into out.
__global__ __launch_bounds__(THREADS) void k_sel(
    const unsigned long long* __restrict__ hist,
    const unsigned int* __restrict__ stats_u, const float* __restrict__ stats_f,
    float* __restrict__ out)
{
    const int row = blockIdx.x;           // 0..63
    const int samp = row & (NSAMP - 1), type = row >> 5;
    const int tid = threadIdx.x;

    unsigned n_pos = stats_u[samp * 4 + type * 2];
    float pos_sum  = stats_f[samp * 4 + type * 2 + 1];
    unsigned n_neg = NPIX - n_pos;
    float pos_part = (n_pos > 0u) ? pos_sum / (float)n_pos : 0.f;
    if (n_neg == 0u) {
        if (tid == 0) atomicAdd(out, (pos_part - 1.f) / (float)NSAMP); // sentinel -1
        return;
    }
    unsigned k;
    if (n_pos > 0u) {
        k = 3u * n_pos;
        if (k > n_neg) k = n_neg;
        if (k < 1u) k = 1u;
    } else {
        k = 500u;   // fallback: top-500 (all pixels are negatives when n_pos==0)
    }

    const unsigned long long* h = hist + ((size_t)samp * 2 + type) * BINS2;
    unsigned c[8]; float s[8];
    #pragma unroll
    for (int j = 0; j < 8; ++j) {
        unsigned long long v = h[BINS2 - 1 - (tid * 8 + j)];  // descending ranks
        c[j] = (unsigned)(v >> 46);
        s[j] = (float)((double)(v & MASK46) * FXINV);
    }
    unsigned tc = 0; float ts = 0.f;
    #pragma unroll
    for (int j = 0; j < 8; ++j) { tc += c[j]; ts += s[j]; }

    unsigned lane = tid & 63, w = tid >> 6;
    unsigned ic = tc; float is = ts;
    #pragma unroll
    for (int off = 1; off < 64; off <<= 1) {
        unsigned uc = __shfl_up(ic, off);
        float    us = __shfl_up(is, off);
        if (lane >= off) { ic += uc; is += us; }
    }
    __shared__ unsigned wtc[4]; __shared__ float wts[4];
    if (lane == 63) { wtc[w] = ic; wts[w] = is; }
    __syncthreads();
    unsigned woc = 0; float wos = 0.f;
    for (unsigned i = 0; i < w; ++i) { woc += wtc[i]; wos += wts[i]; }
    unsigned before_c = woc + ic - tc;   // count strictly above my first rank
    float    before_s = wos + is - ts;

    #pragma unroll
    for (int j = 0; j < 8; ++j) {
        if (before_c < k && before_c + c[j] >= k) {
            unsigned kpp = k - before_c;             // 1 <= kpp <= c[j]
            float mean = s[j] / (float)c[j];
            float topk = before_s + (float)kpp * mean;
            atomicAdd(out, (pos_part + topk / (float)k) / (float)NSAMP);
        }
        before_c += c[j]; before_s += s[j];
    }
}

extern "C" void kernel_launch(void* const* d_in, const int* in_sizes, int n_in,
                              void* d_out, int out_size, void* d_ws, size_t ws_size,
                              hipStream_t stream)
{
    (void)in_sizes; (void)n_in; (void)out_size; (void)ws_size;
    const float* gt_r = (const float*)d_in[0];
    const float* gt_a = (const float*)d_in[1];
    const float* pr_r = (const float*)d_in[2];
    const float* pr_a = (const float*)d_in[3];
    const float* conf = (const float*)d_in[4];

    char* ws = (char*)d_ws;
    unsigned long long* hist = (unsigned long long*)ws;
    unsigned int* stats_u = (unsigned int*)(ws + STATS_OFF);
    float*        stats_f = (float*)       (ws + STATS_OFF);

    int zblocks = (int)((ZERO_BYTES / 16 + THREADS - 1) / THREADS);
    k_zero<<<zblocks, THREADS, 0, stream>>>((uint4*)ws, (float*)d_out);

    dim3 gridH(BLKROW, NSAMP);
    k_hist<<<gridH, THREADS, 0, stream>>>(gt_r, gt_a, pr_r, pr_a, conf,
                                          hist, stats_u, stats_f);
    k_sel<<<2 * NSAMP, THREADS, 0, stream>>>(hist, stats_u, stats_f, (float*)d_out);
}

// Round 6
// 65.078 us; speedup vs baseline: 1.5026x; 1.5026x over previous
//
#include <hip/hip_runtime.h>

#define NPIX (384*384)        // 147456
#define NSAMP 32
#define ROWS 64               // 32 region rows + 32 affinity rows
#define BINS2 2048            // exponent(8) + 4 mantissa bits; l in [0,1) -> bin <= 2031
#define REPL 4                // histogram replication (same-address conflict fix)
#define THREADS 256
#define BLKROW 36
#define EPB (NPIX / BLKROW)   // 4096 elements per block
#define NIT (EPB / (THREADS * 4))   // 4 float4-iterations per thread

#define HIST_BYTES ((size_t)ROWS * BINS2 * 4)   // 512 KB u32 counts
#define STATS_OFF  HIST_BYTES
// stats per row (stride 4 x 4B): 0=n_pos(u32) 1=pos_sum(f32)
#define ZERO_BYTES (STATS_OFF + (size_t)ROWS * 4 * 4)

__global__ __launch_bounds__(THREADS) void k_zero(uint4* __restrict__ ws4,
                                                  float* __restrict__ out)
{
    size_t i = (size_t)blockIdx.x * THREADS + threadIdx.x;
    if (i < ZERO_BYTES / 16) ws4[i] = make_uint4(0u, 0u, 0u, 0u);
    if (i == 0) out[0] = 0.f;
}

// Per (row, chunk) block: compute loss for 4096 pixels, count-only 2048-bin
// LDS histogram (4-way replicated u32), positives wave-reduced to global stats.
__global__ __launch_bounds__(THREADS) void k_hist(
    const float* __restrict__ gt_r, const float* __restrict__ gt_a,
    const float* __restrict__ pr_r, const float* __restrict__ pr_a,
    const float* __restrict__ conf,
    unsigned int* __restrict__ hist,
    unsigned int* __restrict__ stats_u, float* __restrict__ stats_f)
{
    __shared__ unsigned int s_cnt[BINS2 * REPL];   // 32 KB
    const int tid = threadIdx.x;
    const int row = blockIdx.y;
    const int samp = row & (NSAMP - 1);
    const float* gt = (row < NSAMP) ? gt_r : gt_a;
    const float* pr = (row < NSAMP) ? pr_r : pr_a;
    const unsigned copy = tid & (REPL - 1);

    for (int i = tid; i < BINS2 * REPL; i += THREADS) s_cnt[i] = 0u;
    __syncthreads();

    // issue all 12 vector loads up front for max memory-level parallelism
    size_t base = (size_t)samp * NPIX + (size_t)blockIdx.x * EPB + (size_t)tid * 4;
    float4 g[NIT], p[NIT], c[NIT];
    #pragma unroll
    for (int it = 0; it < NIT; ++it) {
        size_t idx = base + (size_t)it * THREADS * 4;
        g[it] = *(const float4*)(gt + idx);
        p[it] = *(const float4*)(pr + idx);
        c[it] = *(const float4*)(conf + idx);
    }

    unsigned pc = 0; float ps = 0.f;
    #pragma unroll
    for (int it = 0; it < NIT; ++it) {
        float gv[4] = {g[it].x, g[it].y, g[it].z, g[it].w};
        float pv[4] = {p[it].x, p[it].y, p[it].z, p[it].w};
        float cv[4] = {c[it].x, c[it].y, c[it].z, c[it].w};
        #pragma unroll
        for (int j = 0; j < 4; ++j) {
            float d = pv[j] - gv[j];
            float l = d * d * cv[j];
            if (gv[j] >= 0.1f) { pc++; ps += l; }
            else {
                unsigned bin = __float_as_uint(l) >> 19;   // l < 1 -> bin <= 2031
                if (bin > BINS2 - 1) bin = BINS2 - 1;      // safety clamp
                atomicAdd(&s_cnt[(bin << 2) | copy], 1u);
            }
        }
    }

    // wave-reduce positive stats, one global atomic per wave
    for (int off = 32; off; off >>= 1) {
        pc += __shfl_down(pc, off);
        ps += __shfl_down(ps, off);
    }
    if ((tid & 63) == 0 && pc) {
        atomicAdd(&stats_u[row * 4 + 0], pc);
        atomicAdd(&stats_f[row * 4 + 1], ps);
    }
    __syncthreads();

    unsigned int* hrow = hist + (size_t)row * BINS2;
    for (int i = tid; i < BINS2; i += THREADS) {
        unsigned v = s_cnt[i << 2] + s_cnt[(i << 2) | 1]
                   + s_cnt[(i << 2) | 2] + s_cnt[(i << 2) | 3];
        if (v) atomicAdd(&hrow[i], v);
    }
}

// Geometric center of histogram bin b (bins are [lo, lo*(1+1/16)) slices).
__device__ __forceinline__ float bin_center(int b)
{
    return __uint_as_float(((unsigned)b) << 19) * 1.03125f;
}

// Per row: parallel descending suffix-scan over 2048 count bins; top-k sum
// approximated as sum(count*center) above the boundary + kpp*center(boundary).
__global__ __launch_bounds__(THREADS) void k_sel(
    const unsigned int* __restrict__ hist,
    const unsigned int* __restrict__ stats_u, const float* __restrict__ stats_f,
    float* __restrict__ out)
{
    const int row = blockIdx.x;           // 0..63
    const int tid = threadIdx.x;

    unsigned n_pos = stats_u[row * 4 + 0];
    float pos_sum  = stats_f[row * 4 + 1];
    unsigned n_neg = NPIX - n_pos;
    float pos_part = (n_pos > 0u) ? pos_sum / (float)n_pos : 0.f;
    if (n_neg == 0u) {
        if (tid == 0) atomicAdd(out, (pos_part - 1.f) / (float)NSAMP); // sentinel -1
        return;
    }
    unsigned k;
    if (n_pos > 0u) {
        k = 3u * n_pos;
        if (k > n_neg) k = n_neg;
        if (k < 1u) k = 1u;
    } else {
        k = 500u;   // fallback: top-500 (all pixels are negatives when n_pos==0)
    }

    const unsigned int* h = hist + (size_t)row * BINS2;
    unsigned c[8]; float s[8];
    #pragma unroll
    for (int j = 0; j < 8; ++j) {
        int bin = BINS2 - 1 - (tid * 8 + j);              // descending ranks
        c[j] = h[bin];
        s[j] = (float)c[j] * bin_center(bin);
    }
    unsigned tc = 0; float ts = 0.f;
    #pragma unroll
    for (int j = 0; j < 8; ++j) { tc += c[j]; ts += s[j]; }

    unsigned lane = tid & 63, w = tid >> 6;
    unsigned ic = tc; float is = ts;
    #pragma unroll
    for (int off = 1; off < 64; off <<= 1) {
        unsigned uc = __shfl_up(ic, off);
        float    us = __shfl_up(is, off);
        if (lane >= off) { ic += uc; is += us; }
    }
    __shared__ unsigned wtc[4]; __shared__ float wts[4];
    if (lane == 63) { wtc[w] = ic; wts[w] = is; }
    __syncthreads();
    unsigned woc = 0; float wos = 0.f;
    for (unsigned i = 0; i < w; ++i) { woc += wtc[i]; wos += wts[i]; }
    unsigned before_c = woc + ic - tc;   // count strictly above my first rank
    float    before_s = wos + is - ts;

    #pragma unroll
    for (int j = 0; j < 8; ++j) {
        if (before_c < k && before_c + c[j] >= k) {
            unsigned kpp = k - before_c;             // 1 <= kpp <= c[j]
            int bin = BINS2 - 1 - (tid * 8 + j);
            float topk = before_s + (float)kpp * bin_center(bin);
            atomicAdd(out, (pos_part + topk / (float)k) / (float)NSAMP);
        }
        before_c += c[j]; before_s += s[j];
    }
}

extern "C" void kernel_launch(void* const* d_in, const int* in_sizes, int n_in,
                              void* d_out, int out_size, void* d_ws, size_t ws_size,
                              hipStream_t stream)
{
    (void)in_sizes; (void)n_in; (void)out_size; (void)ws_size;
    const float* gt_r = (const float*)d_in[0];
    const float* gt_a = (const float*)d_in[1];
    const float* pr_r = (const float*)d_in[2];
    const float* pr_a = (const float*)d_in[3];
    const float* conf = (const float*)d_in[4];

    char* ws = (char*)d_ws;
    unsigned int* hist    = (unsigned int*)ws;
    unsigned int* stats_u = (unsigned int*)(ws + STATS_OFF);
    float*        stats_f = (float*)       (ws + STATS_OFF);

    int zblocks = (int)((ZERO_BYTES / 16 + THREADS - 1) / THREADS);
    k_zero<<<zblocks, THREADS, 0, stream>>>((uint4*)ws, (float*)d_out);

    dim3 gridH(BLKROW, ROWS);
    k_hist<<<gridH, THREADS, 0, stream>>>(gt_r, gt_a, pr_r, pr_a, conf,
                                          hist, stats_u, stats_f);
    k_sel<<<ROWS, THREADS, 0, stream>>>(hist, stats_u, stats_f, (float*)d_out);
}

// Round 7
// 62.679 us; speedup vs baseline: 1.5601x; 1.0383x over previous
//
#include <hip/hip_runtime.h>

#define NPIX (384*384)        // 147456
#define NSAMP 32
#define ROWS 64               // 32 region rows + 32 affinity rows
#define BINS2 2048            // exponent(8) + 4 mantissa bits; l in [0,1) -> bin <= 2031
#define REPL 2                // LDS histogram replication
#define THREADS 256
#define BLKROW 36
#define EPB (NPIX / BLKROW)   // 4096 elements per block
#define NIT (EPB / (THREADS * 4))   // 4 float4-iterations per thread

// workspace: part[ROWS][BLKROW][BINS2] u32 partial histograms (18.9 MB, plain
// stores, never needs zeroing), then stats (per row: 0=n_pos 1=pos_sum).
#define PART_BYTES ((size_t)ROWS * BLKROW * BINS2 * 4)
#define STATS_OFF  PART_BYTES

__global__ __launch_bounds__(THREADS) void k_zero(unsigned int* __restrict__ stats,
                                                  float* __restrict__ out)
{
    int i = threadIdx.x;           // single block
    if (i < ROWS * 4) stats[i] = 0u;
    if (i == 0) out[0] = 0.f;
}

// Per (row, chunk) block: loss for 4096 pixels -> 2048-bin count histogram in
// LDS (2-way replicated), flushed with PLAIN coalesced stores to a private
// partial-histogram slot. No global atomics except tiny per-wave stats.
__global__ __launch_bounds__(THREADS) void k_hist(
    const float* __restrict__ gt_r, const float* __restrict__ gt_a,
    const float* __restrict__ pr_r, const float* __restrict__ pr_a,
    const float* __restrict__ conf,
    unsigned int* __restrict__ part,
    unsigned int* __restrict__ stats_u, float* __restrict__ stats_f)
{
    __shared__ unsigned int s_cnt[BINS2 * REPL];   // 16 KB
    const int tid = threadIdx.x;
    const int row = blockIdx.y;
    const int chunk = blockIdx.x;
    const int samp = row & (NSAMP - 1);
    const float* gt = (row < NSAMP) ? gt_r : gt_a;
    const float* pr = (row < NSAMP) ? pr_r : pr_a;
    const unsigned copy = tid & (REPL - 1);

    for (int i = tid; i < BINS2 * REPL; i += THREADS) s_cnt[i] = 0u;
    __syncthreads();

    size_t base = (size_t)samp * NPIX + (size_t)chunk * EPB + (size_t)tid * 4;
    unsigned pc = 0; float ps = 0.f;
    #pragma unroll
    for (int it = 0; it < NIT; ++it) {
        size_t idx = base + (size_t)it * THREADS * 4;
        float4 g = *(const float4*)(gt + idx);
        float4 p = *(const float4*)(pr + idx);
        float4 c = *(const float4*)(conf + idx);
        float gv[4] = {g.x, g.y, g.z, g.w};
        float pv[4] = {p.x, p.y, p.z, p.w};
        float cv[4] = {c.x, c.y, c.z, c.w};
        #pragma unroll
        for (int j = 0; j < 4; ++j) {
            float d = pv[j] - gv[j];
            float l = d * d * cv[j];
            if (gv[j] >= 0.1f) { pc++; ps += l; }
            else {
                unsigned bin = __float_as_uint(l) >> 19;   // l < 1 -> bin <= 2031
                if (bin > BINS2 - 1) bin = BINS2 - 1;      // safety clamp
                atomicAdd(&s_cnt[(bin << 1) | copy], 1u);
            }
        }
    }

    // wave-reduce positive stats, one global atomic per wave (tiny traffic)
    for (int off = 32; off; off >>= 1) {
        pc += __shfl_down(pc, off);
        ps += __shfl_down(ps, off);
    }
    if ((tid & 63) == 0 && pc) {
        atomicAdd(&stats_u[row * 4 + 0], pc);
        atomicAdd(&stats_f[row * 4 + 1], ps);
    }
    __syncthreads();

    // private flush: plain coalesced stores, zero contention
    unsigned int* dst = part + ((size_t)row * BLKROW + chunk) * BINS2;
    for (int i = tid; i < BINS2; i += THREADS)
        dst[i] = s_cnt[i << 1] + s_cnt[(i << 1) | 1];
}

// Geometric center of histogram bin b (bins are [lo, lo*(1+1/16)) slices).
__device__ __forceinline__ float bin_center(int b)
{
    return __uint_as_float(((unsigned)b) << 19) * 1.03125f;
}

// Per row: sum 36 partial histograms (contiguous uint4 streaming), then
// parallel descending suffix-scan; top-k sum via count*bin_center.
__global__ __launch_bounds__(THREADS) void k_sel(
    const unsigned int* __restrict__ part,
    const unsigned int* __restrict__ stats_u, const float* __restrict__ stats_f,
    float* __restrict__ out)
{
    const int row = blockIdx.x;           // 0..63
    const int tid = threadIdx.x;

    unsigned n_pos = stats_u[row * 4 + 0];
    float pos_sum  = stats_f[row * 4 + 1];
    unsigned n_neg = NPIX - n_pos;
    float pos_part = (n_pos > 0u) ? pos_sum / (float)n_pos : 0.f;
    if (n_neg == 0u) {
        if (tid == 0) atomicAdd(out, (pos_part - 1.f) / (float)NSAMP); // sentinel -1
        return;
    }
    unsigned k;
    if (n_pos > 0u) {
        k = 3u * n_pos;
        if (k > n_neg) k = n_neg;
        if (k < 1u) k = 1u;
    } else {
        k = 500u;   // fallback: top-500 (all pixels are negatives when n_pos==0)
    }

    // accumulate my 8 descending-rank bins over the 36 chunk partials.
    // rank r = tid*8+j  ->  bin = 2047 - r; thread's bins are the contiguous
    // ascending range [2040-8*tid, 2047-8*tid] = two uint4 loads per chunk.
    const unsigned int* base = part + (size_t)row * BLKROW * BINS2;
    unsigned c[8] = {0,0,0,0,0,0,0,0};
    for (int ch = 0; ch < BLKROW; ++ch) {
        const uint4* q = (const uint4*)(base + (size_t)ch * BINS2
                                        + (BINS2 - 8 - tid * 8));
        uint4 lo = q[0], hi = q[1];
        c[0] += hi.w; c[1] += hi.z; c[2] += hi.y; c[3] += hi.x;
        c[4] += lo.w; c[5] += lo.z; c[6] += lo.y; c[7] += lo.x;
    }
    unsigned tc = 0; float ts = 0.f;
    float s[8];
    #pragma unroll
    for (int j = 0; j < 8; ++j) {
        s[j] = (float)c[j] * bin_center(BINS2 - 1 - (tid * 8 + j));
        tc += c[j]; ts += s[j];
    }

    unsigned lane = tid & 63, w = tid >> 6;
    unsigned ic = tc; float is = ts;
    #pragma unroll
    for (int off = 1; off < 64; off <<= 1) {
        unsigned uc = __shfl_up(ic, off);
        float    us = __shfl_up(is, off);
        if (lane >= off) { ic += uc; is += us; }
    }
    __shared__ unsigned wtc[4]; __shared__ float wts[4];
    if (lane == 63) { wtc[w] = ic; wts[w] = is; }
    __syncthreads();
    unsigned woc = 0; float wos = 0.f;
    for (unsigned i = 0; i < w; ++i) { woc += wtc[i]; wos += wts[i]; }
    unsigned before_c = woc + ic - tc;   // count strictly above my first rank
    float    before_s = wos + is - ts;

    #pragma unroll
    for (int j = 0; j < 8; ++j) {
        if (before_c < k && before_c + c[j] >= k) {
            unsigned kpp = k - before_c;             // 1 <= kpp <= c[j]
            int bin = BINS2 - 1 - (tid * 8 + j);
            float topk = before_s + (float)kpp * bin_center(bin);
            atomicAdd(out, (pos_part + topk / (float)k) / (float)NSAMP);
        }
        before_c += c[j]; before_s += s[j];
    }
}

extern "C" void kernel_launch(void* const* d_in, const int* in_sizes, int n_in,
                              void* d_out, int out_size, void* d_ws, size_t ws_size,
                              hipStream_t stream)
{
    (void)in_sizes; (void)n_in; (void)out_size; (void)ws_size;
    const float* gt_r = (const float*)d_in[0];
    const float* gt_a = (const float*)d_in[1];
    const float* pr_r = (const float*)d_in[2];
    const float* pr_a = (const float*)d_in[3];
    const float* conf = (const float*)d_in[4];

    char* ws = (char*)d_ws;
    unsigned int* part    = (unsigned int*)ws;
    unsigned int* stats_u = (unsigned int*)(ws + STATS_OFF);
    float*        stats_f = (float*)       (ws + STATS_OFF);

    k_zero<<<1, THREADS, 0, stream>>>(stats_u, (float*)d_out);

    dim3 gridH(BLKROW, ROWS);
    k_hist<<<gridH, THREADS, 0, stream>>>(gt_r, gt_a, pr_r, pr_a, conf,
                                          part, stats_u, stats_f);
    k_sel<<<ROWS, THREADS, 0, stream>>>(part, stats_u, stats_f, (float*)d_out);
}